// Round 9
// baseline (4490.860 us; speedup 1.0000x reference)
//
#include <hip/hip_runtime.h>
#include <math.h>

// ---------------------------------------------------------------------------
// TDS decoder R9: persistent kernel, 256 blocks x 1024 threads.
// = R4 topology (NG=64 atomic pre-reduction, ONE poller wave per block,
//   single-wave pipelined 64-region gather, LDS go/bf fan-out, register-
//   resident K rows / M columns / aux rows, distributed gh+hp)
// + R8's dense tag publish/poll (41 relaxed atomicAdds -> vmcnt drain ->
//   ONE release tag store into int[3][256]; poll = 4 loads/lane, 16 lines).
// No split gather, no gcnt (R8's regression), no counter RMWs (R4's wart).
// ---------------------------------------------------------------------------

#define NV      40
#define TENC    8192
#define MAXLEN  200
#define EOS_IDX 38
#define NB      256
#define NT      1024
#define NW      16
#define ROWS    32                    /* K rows per block (2 per wave)      */
#define NG      64                    /* groups; 4 blocks add per group     */
#define SCALE   0.04419417382415922f  /* 1/sqrt(512) */

#define WS_TAG  0                     /* int[3][256]                        */
#define WS_GRP  768                   /* float[3][NG*64]                    */
#define WS_HP   13056                 /* float[3][64]                       */
#define WS_GH   13248                 /* float[3][1536]                     */
#define WS_GI   17856                 /* float[40*1536]                     */

__device__ __forceinline__ int ld_tag(const int* p) {
  return __hip_atomic_load(p, __ATOMIC_RELAXED, __HIP_MEMORY_SCOPE_AGENT);
}
__device__ __forceinline__ float ld_af(const float* p) {
  return __hip_atomic_load(p, __ATOMIC_RELAXED, __HIP_MEMORY_SCOPE_AGENT);
}
__device__ __forceinline__ void st_af(float* p, float v) {
  __hip_atomic_store(p, v, __ATOMIC_RELAXED, __HIP_MEMORY_SCOPE_AGENT);
}
__device__ __forceinline__ void st_tag_rel(int* p, int v) {
  __hip_atomic_store(p, v, __ATOMIC_RELEASE, __HIP_MEMORY_SCOPE_AGENT);
}
__device__ __forceinline__ int ld_lds_acq(int* p) {
  return __hip_atomic_load(p, __ATOMIC_ACQUIRE, __HIP_MEMORY_SCOPE_WORKGROUP);
}
__device__ __forceinline__ void st_lds_rel(int* p, int v) {
  __hip_atomic_store(p, v, __ATOMIC_RELEASE, __HIP_MEMORY_SCOPE_WORKGROUP);
}

__device__ __forceinline__ float wred(float s) {
#pragma unroll
  for (int o = 32; o > 0; o >>= 1) s += __shfl_xor(s, o, 64);
  return s;
}
__device__ __forceinline__ float dot8(float4 a0, float4 a1, float4 b0,
                                      float4 b1) {
  return a0.x * b0.x + a0.y * b0.y + a0.z * b0.z + a0.w * b0.w +
         a1.x * b1.x + a1.y * b1.y + a1.z * b1.z + a1.w * b1.w;
}
__device__ __forceinline__ float wdot512(const float* __restrict__ a,
                                         const float* __restrict__ b) {
  const int l = threadIdx.x & 63;
  const float4 a0 = ((const float4*)a)[l];
  const float4 a1 = ((const float4*)a)[l + 64];
  const float4 b0 = ((const float4*)b)[l];
  const float4 b1 = ((const float4*)b)[l + 64];
  return wred(dot8(a0, a1, b0, b1));
}

__global__ void __launch_bounds__(NT, 4) dec_main(
    const float* __restrict__ enc, const float* __restrict__ hidden,
    const float* __restrict__ embed, const float* __restrict__ w_ih,
    const float* __restrict__ w_hh, const float* __restrict__ b_ih,
    const float* __restrict__ b_hh, const float* __restrict__ w_out,
    const float* __restrict__ b_out, float* __restrict__ o,
    float* __restrict__ ws) {
  const int b = blockIdx.x, tid = threadIdx.x;
  const int wave = tid >> 6, lane = tid & 63;
  const int g = b & (NG - 1);
  const int r0 = b * ROWS;
  int* wsi = (int*)ws;

  __shared__ __align__(16) float h_lds[512];
  __shared__ float pw_lds[NW * 64];   // dot-phase fold partials
  __shared__ float sc_lds[1];
  __shared__ int go_lds;              // t+1 when step-t tags all observed
  __shared__ int bf_lds;              // (t<<6)|best

  // ----------------- prologue -----------------
  if (tid < 512) h_lds[tid] = hidden[tid];
  if (tid == 0) { go_lds = 0; bf_lds = -1; }

  // gi_all[v][j] = W_ih[j].embed[v] + b_ih[j]  (240 dots per block)
  for (int u = wave; u < 240; u += NW) {
    const int gl = b * 240 + u;
    const int v = gl / 1536, j = gl - v * 1536;
    const float d = wdot512(w_ih + (size_t)j * 512, embed + (size_t)v * 512);
    if (lane == 0) st_af(&ws[WS_GI + (size_t)v * 1536 + j], d + b_ih[j]);
  }
  // gh(h0): 6 rows (waves 0-5) directly into gh slot 2
  if (wave < 6) {
    const int j = b * 6 + wave;
    const float d = wdot512(w_hh + (size_t)j * 512, hidden);
    if (lane == 0) st_af(&ws[WS_GH + 2 * 1536 + j], d + b_hh[j]);
  }
  // zero group accumulators of slots 0 and 1 (blocks 0..63 own region b)
  if (b < NG) {
    if (wave == 6 && lane < 48) st_af(&ws[WS_GRP + 0 * 4096 + b * 64 + lane], 0.0f);
    if (wave == 7 && lane < 48) st_af(&ws[WS_GRP + 1 * 4096 + b * 64 + lane], 0.0f);
  }
  __syncthreads();  // every wave drains vmcnt before s_barrier
  if (tid == 0) st_tag_rel(wsi + WS_TAG + 2 * 256 + b, 0);

  // --- register-resident K rows and M columns ---
  const float* k0p = enc + (size_t)(r0 + 2 * wave) * 1024;
  const float4 k0a = ((const float4*)k0p)[lane];
  const float4 k0b = ((const float4*)k0p)[lane + 64];
  const float4 k1a = ((const float4*)(k0p + 1024))[lane];
  const float4 k1b = ((const float4*)(k0p + 1024))[lane + 64];
  float Mr0 = (lane == 40) ? 1.0f : 0.0f, Mr1 = Mr0;
  {
    const float* v0p = k0p + 512;
    const float4 va0 = ((const float4*)v0p)[lane];
    const float4 va1 = ((const float4*)v0p)[lane + 64];
    const float4 vb0 = ((const float4*)(v0p + 1024))[lane];
    const float4 vb1 = ((const float4*)(v0p + 1024))[lane + 64];
    for (int v = 0; v < NV; ++v) {
      const float* wp = w_out + (size_t)v * 1024;
      const float4 w0 = ((const float4*)wp)[lane];
      const float4 w1 = ((const float4*)wp)[lane + 64];
      const float sa = wred(dot8(va0, va1, w0, w1));
      const float sb = wred(dot8(vb0, vb1, w0, w1));
      if (lane == v) { Mr0 = sa; Mr1 = sb; }
    }
  }
  // aux row regs: waves 1-6 -> W_hh row; wave 7 -> W_out hp row (blocks 1..40)
  float4 xa0 = {0, 0, 0, 0}, xa1 = {0, 0, 0, 0};
  float xb = 0.0f;
  if (wave >= 1 && wave <= 6) {
    const int j = b * 6 + (wave - 1);
    const float* wp = w_hh + (size_t)j * 512;
    xa0 = ((const float4*)wp)[lane];
    xa1 = ((const float4*)wp)[lane + 64];
    xb = b_hh[j];
  } else if (wave == 7 && b >= 1 && b <= NV) {
    const float* wp = w_out + (size_t)(b - 1) * 1024 + 512;
    xa0 = ((const float4*)wp)[lane];
    xa1 = ((const float4*)wp)[lane + 64];
    xb = b_out[b - 1];
  }

  // ----------------- main loop -----------------
  int eos_reg = -1;            // block0/wave0/lane0 only
  float p0 = 0.0f, p1 = 0.0f;  // this wave's unnormalized attention weights
  float* attn = o + (size_t)MAXLEN * NV + 1;

  for (int t = 0; t <= MAXLEN; ++t) {
    const int s2 = (t + 2) % 3;  // slot holding step-(t-1) publications

    if (wave == 0) {
      // ---- single poller: all 256 tags, 4 independent loads per lane ----
      {
        const int* tp = wsi + WS_TAG + s2 * 256 + lane;
        bool ok = false;
        for (;;) {
          if (!ok) {
            const int a0 = ld_tag(tp);
            const int a1 = ld_tag(tp + 64);
            const int a2 = ld_tag(tp + 128);
            const int a3 = ld_tag(tp + 192);
            ok = ((a0 == t) & (a1 == t) & (a2 == t) & (a3 == t)) != 0;
          }
          if (__ballot(!ok) == 0ull) break;
          __builtin_amdgcn_s_sleep(1);
        }
      }
      if (lane == 0) st_lds_rel(&go_lds, t + 1);  // GRU waves may start loads
      if (t > 0) {
        // hp load (independent, issued before gather chains)
        const float hp =
            (lane < NV) ? ld_af(ws + WS_HP + s2 * 64 + lane) : 0.0f;
        // ---- single-wave pipelined gather: 64 regions, 4 dep chains ----
        const float* rbl = ws + WS_GRP + s2 * 4096 + lane;
        float c0 = 0, c1 = 0, c2 = 0, c3 = 0;
#pragma unroll
        for (int q = 0; q < 16; ++q) {
          c0 += ld_af(rbl + (4 * q + 0) * 64);
          c1 += ld_af(rbl + (4 * q + 1) * 64);
          c2 += ld_af(rbl + (4 * q + 2) * 64);
          c3 += ld_af(rbl + (4 * q + 3) * 64);
        }
        const float cs = (c0 + c1) + (c2 + c3);
        const float S = __shfl(cs, 40, 64);
        const float ov = cs * (1.0f / S) + hp;
        unsigned long long key = 0ull;
        if (lane < NV) {
          unsigned u = __float_as_uint(ov);
          u = (u & 0x80000000u) ? ~u : (u | 0x80000000u);
          key = ((unsigned long long)u << 32) | (unsigned)(~lane);
        }
#pragma unroll
        for (int mm = 32; mm > 0; mm >>= 1) {
          const unsigned long long k2 = __shfl_xor(key, mm, 64);
          if (k2 > key) key = k2;
        }
        const int best = (int)(~(unsigned)key);
        if (lane == 0) sc_lds[0] = S;
        if (b == 0 && lane < NV) o[(size_t)(t - 1) * NV + lane] = ov;
        if (b == 0 && lane == 0) {
          if (best == EOS_IDX && eos_reg < 0) eos_reg = t - 1;
          if (t == MAXLEN)
            o[(size_t)MAXLEN * NV] =
                (eos_reg < 0) ? (float)MAXLEN : (float)eos_reg;
        }
        if (lane == 0) st_lds_rel(&bf_lds, (t << 6) | best);
      } else if (lane == 0) {
        st_lds_rel(&bf_lds, EOS_IDX);  // (0<<6)|EOS
      }
    } else if (wave >= 8 && t < MAXLEN) {
      // ---- GRU waves 8-15: wait go, load gh (coalesced), wait best ----
      const int j = tid - 512;
      while (ld_lds_acq(&go_lds) < t + 1) __builtin_amdgcn_s_sleep(1);
      const float* ghs = ws + WS_GH + s2 * 1536;
      const float ghr = ld_af(ghs + j);
      const float ghz = ld_af(ghs + j + 512);
      const float ghn = ld_af(ghs + j + 1024);
      int bf;
      while (((bf = ld_lds_acq(&bf_lds)) >> 6) < t) __builtin_amdgcn_s_sleep(1);
      const float* gi = ws + WS_GI + (size_t)(bf & 63) * 1536;
      const float gir = gi[j], giz = gi[j + 512], gin = gi[j + 1024];
      const float r = 1.0f / (1.0f + expf(-(gir + ghr)));
      const float z = 1.0f / (1.0f + expf(-(giz + ghz)));
      const float n = tanhf(gin + r * ghn);
      h_lds[j] = (1.0f - z) * n + z * h_lds[j];
    }
    __syncthreads();  // barrier A: h_t, sc_lds ready

    if (t > 0 && lane < 2)  // previous step's normalized attention weights
      attn[(size_t)(t - 1) * TENC + r0 + 2 * wave + lane] =
          (lane ? p1 : p0) * (1.0f / sc_lds[0]);
    if (t == MAXLEN) break;

    // ---- dots: 2 K-dots + fold partial (regs); aux row (regs) ----
    {
      const float4 hh0 = ((const float4*)h_lds)[lane];
      const float4 hh1 = ((const float4*)h_lds)[lane + 64];
      const float d0 = wred(dot8(k0a, k0b, hh0, hh1));
      const float d1 = wred(dot8(k1a, k1b, hh0, hh1));
      p0 = expf(d0 * SCALE);
      p1 = expf(d1 * SCALE);
      pw_lds[wave * 64 + lane] = p0 * Mr0 + p1 * Mr1;
      if (wave >= 1 && wave <= 6) {  // gh_t row for step t+1
        const float d = wred(dot8(xa0, xa1, hh0, hh1));
        if (lane == 0) st_af(&ws[WS_GH + (t % 3) * 1536 + b * 6 + (wave - 1)],
                             d + xb);
      } else if (wave == 7 && b >= 1 && b <= NV) {  // hp row
        const float d = wred(dot8(xa0, xa1, hh0, hh1));
        if (lane == 0) st_af(&ws[WS_HP + (t % 3) * 64 + (b - 1)], d + xb);
      } else if (wave == 15 && b < NG && lane < 48) {
        // zero group region b of slot (t+1)%3 (provably consumed)
        st_af(&ws[WS_GRP + ((t + 1) % 3) * 4096 + b * 64 + lane], 0.0f);
      }
    }
    __syncthreads();  // barrier C: pw complete, ALL waves' stores drained

    // ---- wave0: reduce, atomic publish, release tag ----
    if (wave == 0) {
      float red = 0.0f;
#pragma unroll
      for (int w2 = 0; w2 < NW; ++w2) red += pw_lds[w2 * 64 + lane];
      if (lane <= 40)
        atomicAdd(&ws[WS_GRP + (t % 3) * 4096 + g * 64 + lane], red);
      if (lane == 0)
        st_tag_rel(wsi + WS_TAG + (t % 3) * 256 + b, t + 1);
    }
  }
}

extern "C" void kernel_launch(void* const* d_in, const int* in_sizes, int n_in,
                              void* d_out, int out_size, void* d_ws,
                              size_t ws_size, hipStream_t stream) {
  const float* enc    = (const float*)d_in[0];
  const float* hidden = (const float*)d_in[1];
  const float* embed  = (const float*)d_in[2];
  const float* w_ih   = (const float*)d_in[3];
  const float* w_hh   = (const float*)d_in[4];
  const float* b_ih   = (const float*)d_in[5];
  const float* b_hh   = (const float*)d_in[6];
  const float* w_out  = (const float*)d_in[7];
  const float* b_out  = (const float*)d_in[8];
  float* out = (float*)d_out;
  float* ws  = (float*)d_ws;

  dec_main<<<dim3(NB), dim3(NT), 0, stream>>>(enc, hidden, embed, w_ih, w_hh,
                                              b_ih, b_hh, w_out, b_out, out,
                                              ws);
}